// Round 21
// baseline (92.142 us; speedup 1.0000x reference)
//
#include <hip/hip_runtime.h>
#include <hip/hip_bf16.h>

// Problem constants (fixed by the reference):
constexpr int NB = 256;   // batch
constexpr int SQ = 512;   // sequence length
constexpr int ED = 512;   // encoder dim
constexpr int DD = 512;   // decoder dim
constexpr int UU = 64;    // attention units
constexpr int NT = 32;    // 16-row tiles per batch

typedef __attribute__((ext_vector_type(8))) short bf16x8;
typedef __attribute__((ext_vector_type(4))) float f32x4;

#define MEMFENCE asm volatile("" ::: "memory")
#define SBAR do { MEMFENCE; __builtin_amdgcn_s_barrier(); MEMFENCE; } while (0)
#define WAITVM(n) asm volatile("s_waitcnt vmcnt(" #n ")" ::: "memory")
#define WAITLGKM do { asm volatile("s_waitcnt lgkmcnt(0)" ::: "memory"); \
                      __builtin_amdgcn_sched_barrier(0); } while (0)

__device__ __forceinline__ void stage16(const void* g, void* l) {
  __builtin_amdgcn_global_load_lds(
      (const __attribute__((address_space(1))) void*)g,
      (__attribute__((address_space(3))) void*)l, 16, 0, 0);
}

__device__ __forceinline__ unsigned short bf16_rne(float f) {
  unsigned int u = __float_as_uint(f);
  u += 0x7FFFu + ((u >> 16) & 1u);
  return (unsigned short)(u >> 16);
}

// Pack two fp32 -> one dword of 2x bf16 (RNE). Compiles to v_cvt_pk_bf16_f32.
__device__ __forceinline__ unsigned int pack2(float lo, float hi) {
  __hip_bfloat162 h = __float22bfloat162_rn(make_float2(lo, hi));
  return *reinterpret_cast<unsigned int*>(&h);
}

// ws layout (bytes):
constexpr size_t WS_DEC   = 131072;
constexpr size_t WS_LBUF  = 196608;
constexpr size_t WS_CTILE = 262144;

// ---------------------------------------------------------------------------
// Kernel P: fused prep. Blocks 0..127: w2 -> bf16-hi B-fragments
// (layout: ks*2048 + nt*512 + lane*8 + j). Blocks 128..383: dec_proj.
// ---------------------------------------------------------------------------
__global__ __launch_bounds__(256) void prep_all(
    const float* __restrict__ w2, unsigned short* __restrict__ wsb,
    const float* __restrict__ dh, const float* __restrict__ w1,
    const float* __restrict__ w1b, const float* __restrict__ w2b,
    float* __restrict__ dec_ws) {
  const int blk = blockIdx.x;
  __shared__ float red[256];
  if (blk < 128) {
    int tid = blk * 256 + threadIdx.x;   // 0..32767
    int j    = tid & 7;
    int lane = (tid >> 3) & 63;
    int nt   = (tid >> 9) & 3;
    int ks   = tid >> 11;
    int e = ks * 32 + (lane >> 4) * 8 + j;
    int u = nt * 16 + (lane & 15);
    wsb[tid] = bf16_rne(w2[e * UU + u]);
  } else {
    const int b = blk - 128;
    const int t = threadIdx.x;
    const int wave = t >> 6;
    const float* dhb = dh + (size_t)b * DD;
    const int e0 = wave * 128;
    float s = 0.f;
    #pragma unroll 8
    for (int i = 0; i < 128; ++i) {
      int e = e0 + i;
      s = fmaf(dhb[e], w1[e * UU + (t & 63)], s);
    }
    red[t] = s;
    __syncthreads();
    if (t < 64) {
      float d = w1b[t] + w2b[t] + red[t] + red[64 + t] + red[128 + t] + red[192 + t];
      dec_ws[b * UU + t] = d;
    }
  }
}

// ---------------------------------------------------------------------------
// Kernel A: 2048 blocks, 256 threads = 4 waves; block = 4 consecutive
// 16-row tiles, PIPELINED on the r19 base (79.3 us):
//  - double-buffered 2x32 KB slab; tile i+2 staged after tile i's last
//    read; counted WAITVM(8) at loop top (never 0 mid-loop) + raw
//    s_barrier so prefetches survive barriers. r19's bursty
//    stage->drain->compute left the HBM pipe idle ~40% (4 TB/s effective).
//  - FIFO invariant: at iter-i top, ops newer than tile i's stages are
//    only t(i+1)'s 8 (+epilogue stores, which are OLDER) -> vmcnt(8)
//    guarantees tile i resident. B-frags/scalars prefetched BEFORE the
//    first stage so they sit oldest in the FIFO.
//  - internal LDS barriers: explicit lgkmcnt(0)+sched_barrier (rule 18).
//  - compute per tile = r19 verbatim: 2x2 hybrid split, cvt_pk bf16 A,
//    4 KB red4 exchange, const-shift softmax M = sum|v|, column-split
//    context from the same slab (read-once).
// LDS 69.8 KB -> 2 blocks/CU, staging continuously in flight.
// ---------------------------------------------------------------------------
__global__ __launch_bounds__(256, 2) void attn_tile(
    const float* __restrict__ x,
    const float* __restrict__ vk,
    const unsigned short* __restrict__ wsb,
    const float* __restrict__ dec_ws,
    float* __restrict__ lbuf,
    float* __restrict__ ctile,
    float* __restrict__ out)
{
  const int b  = blockIdx.x >> 3;
  const int q8 = blockIdx.x & 7;       // tile group: tiles q8*4 .. q8*4+3
  const int t = threadIdx.x;
  const int wave = t >> 6;
  const int lane = t & 63;
  const int ul = lane & 15;            // A row select / col-in-strip
  const int g  = lane >> 4;            // k-subgroup / row group
  const int swz = (ul & 7) << 4;
  const int kw = wave >> 1;            // k-half
  const int nw = wave & 1;             // u-half

  __shared__ __align__(16) unsigned char slab[2][16][2048];  // 64 KB
  __shared__ __align__(16) f32x4 red4[4][64];                // 4 KB
  __shared__ float psum[2][16];                              // 128 B

  const char* gbase = (const char*)x + (size_t)(b * SQ + q8 * 64) * 2048;

  // ---- B/scalar prefetch FIRST (oldest in vm FIFO) ------------------------
  const unsigned short* bp = wsb + lane * 8;
  bf16x8 bf[8][2];
  #pragma unroll
  for (int i = 0; i < 8; ++i) {
    #pragma unroll
    for (int j = 0; j < 2; ++j)
      bf[i][j] = *(const bf16x8*)(bp + (kw * 8 + i) * 2048 + (nw * 2 + j) * 512);
  }
  float dvs[2], vvs[2];
  #pragma unroll
  for (int j = 0; j < 2; ++j) {
    dvs[j] = dec_ws[b * UU + (nw * 2 + j) * 16 + ul];
    vvs[j] = vk[(nw * 2 + j) * 16 + ul];
  }
  float av = fabsf(vk[lane]);
  av += __shfl_xor(av, 1);
  av += __shfl_xor(av, 2);
  av += __shfl_xor(av, 4);
  av += __shfl_xor(av, 8);
  av += __shfl_xor(av, 16);
  av += __shfl_xor(av, 32);
  const float M = av;                  // exact bound: |score| <= sum|v|

  // stage tile i (group-local) into slab[buf]; wave stages its 4 rows.
  auto stageT = [&](int i, int buf) {
    #pragma unroll
    for (int r = 0; r < 4; ++r) {
      int row = wave * 4 + r;
      #pragma unroll
      for (int h = 0; h < 2; ++h) {
        int off = h * 1024 + lane * 16;
        stage16(gbase + (size_t)(i * 16 + row) * 2048 + (size_t)(off ^ ((row & 7) << 4)),
                &slab[buf][row][off]);
      }
    }
  };

  stageT(0, 0);
  stageT(1, 1);

  const f32x4 zero4 = {0.f, 0.f, 0.f, 0.f};

  #pragma unroll
  for (int i = 0; i < 4; ++i) {
    if (i < 3) { WAITVM(8); } else { WAITVM(0); }   // tile i resident (own wave)
    SBAR;                                            // => resident for all waves
    const int buf = i & 1;
    const int tl = q8 * 4 + i;

    // ---- hybrid projection: 8 k-steps x 2 n-strips per wave ---------------
    f32x4 acc[2];
    acc[0] = zero4;
    acc[1] = zero4;
    const unsigned char* Ab = &slab[buf][ul][0];
    #pragma unroll
    for (int i2 = 0; i2 < 8; ++i2) {
      const int k = kw * 8 + i2;
      f32x4 a0 = *(const f32x4*)(Ab + ((g * 32 + k * 128) ^ swz));
      f32x4 a1 = *(const f32x4*)(Ab + ((g * 32 + k * 128 + 16) ^ swz));
      unsigned int w4[4];
      w4[0] = pack2(a0[0], a0[1]);
      w4[1] = pack2(a0[2], a0[3]);
      w4[2] = pack2(a1[0], a1[1]);
      w4[3] = pack2(a1[2], a1[3]);
      bf16x8 ahi;
      memcpy(&ahi, w4, 16);
      acc[0] = __builtin_amdgcn_mfma_f32_16x16x32_bf16(ahi, bf[i2][0], acc[0], 0, 0, 0);
      acc[1] = __builtin_amdgcn_mfma_f32_16x16x32_bf16(ahi, bf[i2][1], acc[1], 0, 0, 0);
    }

    // ---- cross-k-half reduce: kw=0 publishes 4 KB, kw=1 finalizes ---------
    if (kw == 0) {
      red4[nw * 2 + 0][lane] = acc[0];
      red4[nw * 2 + 1][lane] = acc[1];
    }
    WAITLGKM;
    SBAR;
    if (kw == 1) {
      #pragma unroll
      for (int j = 0; j < 2; ++j) {
        f32x4 o = red4[nw * 2 + j][lane];
        acc[j][0] += o[0];
        acc[j][1] += o[1];
        acc[j][2] += o[2];
        acc[j][3] += o[3];
      }
      // per-strip score partials: row = g*4 + r, col u = (nw*2+j)*16 + ul
      #pragma unroll
      for (int r = 0; r < 4; ++r) {
        float s = 0.f;
        #pragma unroll
        for (int j = 0; j < 2; ++j) {
          float z = acc[j][r] + dvs[j];
          float ez = __expf(2.f * z);              // tanh via exp
          float th = 1.f - 2.f / (ez + 1.f);
          s = fmaf(th, vvs[j], s);
        }
        s += __shfl_xor(s, 1);
        s += __shfl_xor(s, 2);
        s += __shfl_xor(s, 4);
        s += __shfl_xor(s, 8);
        if (ul == 0) psum[nw][g * 4 + r] = s;
      }
    }
    WAITLGKM;
    SBAR;                              // psum complete

    // ---- full scores + bounded-shift softmax (all waves, replicated) ------
    float p[4];
    float lsum = 0.f;
    #pragma unroll
    for (int r = 0; r < 4; ++r) {
      int row = g * 4 + r;
      float sc = psum[0][row] + psum[1][row];
      p[r] = __expf(sc - M);
      lsum += p[r];
    }
    lsum += __shfl_xor(lsum, 16);
    lsum += __shfl_xor(lsum, 32);      // sum over row groups
    lsum += __shfl_xor(lsum, 1);
    lsum += __shfl_xor(lsum, 2);
    lsum += __shfl_xor(lsum, 4);
    lsum += __shfl_xor(lsum, 8);
    lsum *= 0.0625f;                   // 16 duplicated lanes per group

    if (wave == 0 && ul == 0) {
      float* att = out + (size_t)NB * ED + (size_t)b * SQ + tl * 16;
      #pragma unroll
      for (int r = 0; r < 4; ++r) att[g * 4 + r] = p[r];   // unnormalized
    }
    if (t == 0) lbuf[b * NT + tl] = lsum;

    // ---- context from the SAME slab, column-split -------------------------
    {
      const int cbase = wave * 512 + lane * 8;   // byte offset within a row
      float cx = 0.f, cy = 0.f;
      #pragma unroll
      for (int rr = 0; rr < 16; ++rr) {
        const float2 v = *(const float2*)&slab[buf][rr][cbase ^ ((rr & 7) << 4)];
        float pi = __shfl(p[rr & 3], (rr >> 2) << 4);
        cx = fmaf(pi, v.x, cx);
        cy = fmaf(pi, v.y, cy);
      }
      float* ct = ctile + ((size_t)b * NT + tl) * ED + wave * 128 + lane * 2;
      *(float2*)ct = make_float2(cx, cy);
    }

    SBAR;                              // all waves done reading slab[buf]
    if (i < 2) stageT(i + 2, buf);     // safe: reads of buf retired
  }
}

// ---------------------------------------------------------------------------
// Kernel B: combine. All tiles share the shift M, so L = sum of tile sums;
// att *= 1/L in place; ctx = (sum_t ctile_t) / L.
// ---------------------------------------------------------------------------
__global__ __launch_bounds__(256) void combine(
    const float* __restrict__ lbuf,
    const float* __restrict__ ctile, float* __restrict__ out) {
  const int b = blockIdx.x;
  const int t = threadIdx.x;

  float L = 0.f;
  #pragma unroll 8
  for (int j = 0; j < NT; ++j) L += lbuf[b * NT + j];
  const float inv = 1.f / L;

  float* att = out + (size_t)NB * ED + (size_t)b * SQ;
  #pragma unroll
  for (int s = t; s < SQ; s += 256) att[s] *= inv;

  const float* ct = ctile + (size_t)b * NT * ED;
  #pragma unroll
  for (int e = t; e < ED; e += 256) {
    float c = 0.f;
    #pragma unroll 8
    for (int j = 0; j < NT; ++j) c += ct[j * ED + e];
    out[(size_t)b * ED + e] = c * inv;
  }
}

// ---------------------------------------------------------------------------
extern "C" void kernel_launch(void* const* d_in, const int* in_sizes, int n_in,
                              void* d_out, int out_size, void* d_ws, size_t ws_size,
                              hipStream_t stream) {
  const float* dh  = (const float*)d_in[0];
  const float* x   = (const float*)d_in[1];
  const float* w1  = (const float*)d_in[2];
  const float* w1b = (const float*)d_in[3];
  const float* w2  = (const float*)d_in[4];
  const float* w2b = (const float*)d_in[5];
  const float* vk  = (const float*)d_in[6];
  // d_in[7] = v_bias: softmax exactly invariant -> unused.
  unsigned short* wsb = (unsigned short*)d_ws;
  float* dec_ws = (float*)((char*)d_ws + WS_DEC);
  float* lbuf   = (float*)((char*)d_ws + WS_LBUF);
  float* ctile  = (float*)((char*)d_ws + WS_CTILE);
  float* out = (float*)d_out;

  prep_all<<<384, 256, 0, stream>>>(w2, wsb, dh, w1, w1b, w2b, dec_ws);
  attn_tile<<<NB * 8, 256, 0, stream>>>(x, vk, wsb, dec_ws, lbuf, ctile, out);
  combine<<<NB, 256, 0, stream>>>(lbuf, ctile, out);
}

// Round 22
// 77.382 us; speedup vs baseline: 1.1907x; 1.1907x over previous
//
#include <hip/hip_runtime.h>
#include <hip/hip_bf16.h>

// Problem constants (fixed by the reference):
constexpr int NB = 256;   // batch
constexpr int SQ = 512;   // sequence length
constexpr int ED = 512;   // encoder dim
constexpr int DD = 512;   // decoder dim
constexpr int UU = 64;    // attention units
constexpr int NT = 32;    // 16-row tiles per batch

typedef __attribute__((ext_vector_type(8))) short bf16x8;
typedef __attribute__((ext_vector_type(4))) float f32x4;

__device__ __forceinline__ void stage16(const void* g, void* l) {
  __builtin_amdgcn_global_load_lds(
      (const __attribute__((address_space(1))) void*)g,
      (__attribute__((address_space(3))) void*)l, 16, 0, 0);
}

__device__ __forceinline__ unsigned short bf16_rne(float f) {
  unsigned int u = __float_as_uint(f);
  u += 0x7FFFu + ((u >> 16) & 1u);
  return (unsigned short)(u >> 16);
}

// Pack two fp32 -> one dword of 2x bf16 (RNE). Compiles to v_cvt_pk_bf16_f32.
__device__ __forceinline__ unsigned int pack2(float lo, float hi) {
  __hip_bfloat162 h = __float22bfloat162_rn(make_float2(lo, hi));
  return *reinterpret_cast<unsigned int*>(&h);
}

// ws layout (bytes):
constexpr size_t WS_DEC   = 131072;   // dec[256][64]
constexpr size_t WS_MSUM  = 196604;   // one float: M = sum|v|
constexpr size_t WS_LBUF  = 196608;   // lbuf[256][32]
constexpr size_t WS_CTILE = 262144;   // ctile[256][32][512]

// ---------------------------------------------------------------------------
// Kernel P: fused prep. Blocks 0..127: w2 -> bf16-hi B-fragments
// (layout: ks*2048 + nt*512 + lane*8 + j). Blocks 128..383: dec_proj.
// Block 128 additionally computes M = sum|v| once (r22: hoisted out of all
// 8192 attn-block prologues).
// ---------------------------------------------------------------------------
__global__ __launch_bounds__(256) void prep_all(
    const float* __restrict__ w2, unsigned short* __restrict__ wsb,
    const float* __restrict__ dh, const float* __restrict__ w1,
    const float* __restrict__ w1b, const float* __restrict__ w2b,
    const float* __restrict__ vk,
    float* __restrict__ dec_ws, float* __restrict__ msum_ws) {
  const int blk = blockIdx.x;
  __shared__ float red[256];
  if (blk < 128) {
    int tid = blk * 256 + threadIdx.x;   // 0..32767
    int j    = tid & 7;
    int lane = (tid >> 3) & 63;
    int nt   = (tid >> 9) & 3;
    int ks   = tid >> 11;
    int e = ks * 32 + (lane >> 4) * 8 + j;
    int u = nt * 16 + (lane & 15);
    wsb[tid] = bf16_rne(w2[e * UU + u]);
  } else {
    const int b = blk - 128;
    const int t = threadIdx.x;
    const int wave = t >> 6;
    const float* dhb = dh + (size_t)b * DD;
    const int e0 = wave * 128;
    float s = 0.f;
    #pragma unroll 8
    for (int i = 0; i < 128; ++i) {
      int e = e0 + i;
      s = fmaf(dhb[e], w1[e * UU + (t & 63)], s);
    }
    red[t] = s;
    __syncthreads();
    if (t < 64) {
      float d = w1b[t] + w2b[t] + red[t] + red[64 + t] + red[128 + t] + red[192 + t];
      dec_ws[b * UU + t] = d;
    }
    if (blk == 128 && t < 64) {
      float a = fabsf(vk[t]);
      a += __shfl_xor(a, 1);
      a += __shfl_xor(a, 2);
      a += __shfl_xor(a, 4);
      a += __shfl_xor(a, 8);
      a += __shfl_xor(a, 16);
      a += __shfl_xor(a, 32);
      if (t == 0) msum_ws[0] = a;    // exact bound: |score| <= sum|v|
    }
  }
}

// ---------------------------------------------------------------------------
// Kernel A: 8192 blocks, 256 threads = 4 waves, ONE 16-row tile per block.
// r19 (79.3 us, session best) VERBATIM except M loaded from ws (uniform
// s_load) instead of per-block recompute. Design-family optimum per
// r15..r21 sweep: 4 burst-staged independent blocks/CU beat every deeper
// pipeline / higher-wave / different-split variant tried.
// Stack: read-once 32 KB slab (proj AND context), 2x2 hybrid split
// (kw=w>>1, nw=w&1), cvt_pk bf16-RNE A path, 4 KB cross-k reduce,
// const-shift softmax M = sum|v|, column-split context, 4 blocks/CU.
// ---------------------------------------------------------------------------
__global__ __launch_bounds__(256, 4) void attn_tile(
    const float* __restrict__ x,
    const float* __restrict__ vk,
    const unsigned short* __restrict__ wsb,
    const float* __restrict__ dec_ws,
    const float* __restrict__ msum_ws,
    float* __restrict__ lbuf,
    float* __restrict__ ctile,
    float* __restrict__ out)
{
  const int bid = blockIdx.x;
  const int b  = bid >> 5;
  const int tl = bid & 31;
  const int t = threadIdx.x;
  const int wave = t >> 6;
  const int lane = t & 63;
  const int ul = lane & 15;            // A row select / col-in-strip
  const int g  = lane >> 4;            // k-subgroup / row group
  const int swz = (ul & 7) << 4;
  const int kw = wave >> 1;            // k-half
  const int nw = wave & 1;             // u-half

  __shared__ __align__(16) unsigned char slab[16][2048];  // 32 KB
  __shared__ __align__(16) f32x4 red4[4][64];             // 4 KB
  __shared__ float psum[2][16];                           // 128 B

  const char* gsrc = (const char*)x + (size_t)(b * SQ + tl * 16) * 2048;

  // ---- stage: wave w -> rows [w*4, w*4+4), source-XOR per row -------------
  #pragma unroll
  for (int r = 0; r < 4; ++r) {
    int row = wave * 4 + r;
    #pragma unroll
    for (int h = 0; h < 2; ++h) {
      int off = h * 1024 + lane * 16;
      stage16(gsrc + (size_t)row * 2048 + (size_t)(off ^ ((row & 7) << 4)),
              &slab[row][off]);
    }
  }

  // ---- register prefetch (L2) while DMAs fly ------------------------------
  // B frags: wave needs k = kw*8+i, n = nw*2+j.
  const unsigned short* bp = wsb + lane * 8;
  bf16x8 bf[8][2];
  #pragma unroll
  for (int i = 0; i < 8; ++i) {
    #pragma unroll
    for (int j = 0; j < 2; ++j)
      bf[i][j] = *(const bf16x8*)(bp + (kw * 8 + i) * 2048 + (nw * 2 + j) * 512);
  }
  float dvs[2], vvs[2];
  #pragma unroll
  for (int j = 0; j < 2; ++j) {
    dvs[j] = dec_ws[b * UU + (nw * 2 + j) * 16 + ul];
    vvs[j] = vk[(nw * 2 + j) * 16 + ul];
  }
  const float M = msum_ws[0];          // uniform scalar (precomputed once)

  __syncthreads();                     // slab fully resident (drains vmcnt)

  // ---- hybrid projection: 8 k-steps x 2 n-strips per wave -----------------
  const f32x4 zero4 = {0.f, 0.f, 0.f, 0.f};
  f32x4 acc[2];
  acc[0] = zero4;
  acc[1] = zero4;

  const unsigned char* Ab = &slab[ul][0];
  #pragma unroll
  for (int i = 0; i < 8; ++i) {
    const int k = kw * 8 + i;
    f32x4 a0 = *(const f32x4*)(Ab + ((g * 32 + k * 128) ^ swz));
    f32x4 a1 = *(const f32x4*)(Ab + ((g * 32 + k * 128 + 16) ^ swz));
    unsigned int w4[4];
    w4[0] = pack2(a0[0], a0[1]);
    w4[1] = pack2(a0[2], a0[3]);
    w4[2] = pack2(a1[0], a1[1]);
    w4[3] = pack2(a1[2], a1[3]);
    bf16x8 ahi;
    memcpy(&ahi, w4, 16);
    acc[0] = __builtin_amdgcn_mfma_f32_16x16x32_bf16(ahi, bf[i][0], acc[0], 0, 0, 0);
    acc[1] = __builtin_amdgcn_mfma_f32_16x16x32_bf16(ahi, bf[i][1], acc[1], 0, 0, 0);
  }

  // ---- cross-k-half reduce: kw=0 publishes 4 KB, kw=1 finalizes -----------
  if (kw == 0) {
    red4[nw * 2 + 0][lane] = acc[0];
    red4[nw * 2 + 1][lane] = acc[1];
  }
  __syncthreads();
  if (kw == 1) {
    #pragma unroll
    for (int j = 0; j < 2; ++j) {
      f32x4 o = red4[nw * 2 + j][lane];
      acc[j][0] += o[0];
      acc[j][1] += o[1];
      acc[j][2] += o[2];
      acc[j][3] += o[3];
    }
    // per-strip score partials: row = g*4 + r, col u = (nw*2+j)*16 + ul
    #pragma unroll
    for (int r = 0; r < 4; ++r) {
      float s = 0.f;
      #pragma unroll
      for (int j = 0; j < 2; ++j) {
        float z = acc[j][r] + dvs[j];
        float ez = __expf(2.f * z);              // tanh via exp
        float th = 1.f - 2.f / (ez + 1.f);
        s = fmaf(th, vvs[j], s);
      }
      s += __shfl_xor(s, 1);
      s += __shfl_xor(s, 2);
      s += __shfl_xor(s, 4);
      s += __shfl_xor(s, 8);
      if (ul == 0) psum[nw][g * 4 + r] = s;
    }
  }
  __syncthreads();                     // psum complete

  // ---- full scores + bounded-shift softmax (all waves, replicated) --------
  float p[4];
  float lsum = 0.f;
  #pragma unroll
  for (int r = 0; r < 4; ++r) {
    int row = g * 4 + r;
    float sc = psum[0][row] + psum[1][row];
    p[r] = __expf(sc - M);
    lsum += p[r];
  }
  lsum += __shfl_xor(lsum, 16);
  lsum += __shfl_xor(lsum, 32);        // sum over row groups
  lsum += __shfl_xor(lsum, 1);
  lsum += __shfl_xor(lsum, 2);
  lsum += __shfl_xor(lsum, 4);
  lsum += __shfl_xor(lsum, 8);
  lsum *= 0.0625f;                     // 16 duplicated lanes per group

  if (wave == 0 && ul == 0) {
    float* att = out + (size_t)NB * ED + (size_t)b * SQ + tl * 16;
    #pragma unroll
    for (int r = 0; r < 4; ++r) att[g * 4 + r] = p[r];   // unnormalized
  }
  if (t == 0) lbuf[b * NT + tl] = lsum;

  // ---- context from the SAME slab, column-split: wave w cols [w*128,+128) -
  {
    const int cbase = wave * 512 + lane * 8;   // byte offset within a row
    float cx = 0.f, cy = 0.f;
    #pragma unroll
    for (int rr = 0; rr < 16; ++rr) {
      const float2 v = *(const float2*)&slab[rr][cbase ^ ((rr & 7) << 4)];
      float pi = __shfl(p[rr & 3], (rr >> 2) << 4);
      cx = fmaf(pi, v.x, cx);
      cy = fmaf(pi, v.y, cy);
    }
    float* ct = ctile + ((size_t)b * NT + tl) * ED + wave * 128 + lane * 2;
    ct[0] = cx;
    ct[1] = cy;
  }
}

// ---------------------------------------------------------------------------
// Kernel B: combine. All tiles share the shift M, so L = sum of tile sums;
// att *= 1/L in place; ctx = (sum_t ctile_t) / L.
// ---------------------------------------------------------------------------
__global__ __launch_bounds__(256) void combine(
    const float* __restrict__ lbuf,
    const float* __restrict__ ctile, float* __restrict__ out) {
  const int b = blockIdx.x;
  const int t = threadIdx.x;

  float L = 0.f;
  #pragma unroll 8
  for (int j = 0; j < NT; ++j) L += lbuf[b * NT + j];
  const float inv = 1.f / L;

  float* att = out + (size_t)NB * ED + (size_t)b * SQ;
  #pragma unroll
  for (int s = t; s < SQ; s += 256) att[s] *= inv;

  const float* ct = ctile + (size_t)b * NT * ED;
  #pragma unroll
  for (int e = t; e < ED; e += 256) {
    float c = 0.f;
    #pragma unroll 8
    for (int j = 0; j < NT; ++j) c += ct[j * ED + e];
    out[(size_t)b * ED + e] = c * inv;
  }
}

// ---------------------------------------------------------------------------
extern "C" void kernel_launch(void* const* d_in, const int* in_sizes, int n_in,
                              void* d_out, int out_size, void* d_ws, size_t ws_size,
                              hipStream_t stream) {
  const float* dh  = (const float*)d_in[0];
  const float* x   = (const float*)d_in[1];
  const float* w1  = (const float*)d_in[2];
  const float* w1b = (const float*)d_in[3];
  const float* w2  = (const float*)d_in[4];
  const float* w2b = (const float*)d_in[5];
  const float* vk  = (const float*)d_in[6];
  // d_in[7] = v_bias: softmax exactly invariant -> unused.
  unsigned short* wsb = (unsigned short*)d_ws;
  float* dec_ws  = (float*)((char*)d_ws + WS_DEC);
  float* msum_ws = (float*)((char*)d_ws + WS_MSUM);
  float* lbuf    = (float*)((char*)d_ws + WS_LBUF);
  float* ctile   = (float*)((char*)d_ws + WS_CTILE);
  float* out = (float*)d_out;

  prep_all<<<384, 256, 0, stream>>>(w2, wsb, dh, w1, w1b, w2b, vk, dec_ws, msum_ws);
  attn_tile<<<NB * NT, 256, 0, stream>>>(x, vk, wsb, dec_ws, msum_ws, lbuf, ctile, out);
  combine<<<NB, 256, 0, stream>>>(lbuf, ctile, out);
}